// Round 4
// baseline (222.216 us; speedup 1.0000x reference)
//
#include <hip/hip_runtime.h>
#include <hip/hip_bf16.h>

// C[32768,2304] = A[32768,768] * W^T + b ; outputs q,k,v [32768,768] fp32 each.
#define M_TOT 32768
#define K_TOT 768
#define N_TOT 2304
#define H     768
#define BM 128
#define BN 256
#define BK 64
#define NBN 9                    // N_TOT/BN
#define NBM 256                  // M_TOT/BM
#define NBLK (NBM*NBN)           // 2304, %8==0 -> XCD swizzle bijective
#define NKT  (K_TOT/BK)          // 12
#define TILE_ELEMS 8192          // 128 rows x 64 k (packing granule)
#define OUT_PER 25165824         // M_TOT*H

typedef __attribute__((ext_vector_type(8))) short bf16x8;
typedef __attribute__((ext_vector_type(8))) unsigned short u16x8;
typedef __attribute__((ext_vector_type(4))) float f32x4;

__device__ __forceinline__ void gld_lds16(const void* g, void* l) {
    __builtin_amdgcn_global_load_lds(
        (const __attribute__((address_space(1))) unsigned int*)g,
        (__attribute__((address_space(3))) unsigned int*)l,
        16, 0, 0);
}

__device__ __forceinline__ unsigned short f2bf_rne(float f) {
    unsigned u = __builtin_bit_cast(unsigned, f);
    unsigned r = (u + 0x7FFFu + ((u >> 16) & 1u)) >> 16;
    return (unsigned short)r;
}

// ---------------------------------------------------------------------------
// Pass 1 (unchanged from R3, works ~25us): fp32 -> bf16 convert + pack into
// LDS-ready tiled layout pk[tile][kb][row][8], tile = 128 rows x 64 k.
// ---------------------------------------------------------------------------
#define A_TILES 3072             // 256 m-tiles x 12 k-tiles
#define W_TILES 216              // 18 row-tiles x 12 k-tiles
#define LDSW 68

__global__ void convert_pack(const float* __restrict__ A,
                             const float* __restrict__ wq, const float* __restrict__ wk,
                             const float* __restrict__ wv,
                             const float* __restrict__ bq, const float* __restrict__ bk,
                             const float* __restrict__ bv,
                             unsigned short* __restrict__ A_pk,
                             unsigned short* __restrict__ W_pk,
                             float* __restrict__ biasb) {
    __shared__ float lds_f[128 * LDSW];

    const int tid = threadIdx.x;
    const int t   = blockIdx.x;

    int gt = t * 256 + tid;
    if (gt < 2304) {
        biasb[gt] = (gt < 768) ? bq[gt] : (gt < 1536) ? bk[gt - 768] : bv[gt - 1536];
    }

    const float* src;
    unsigned short* dst;
    if (t < A_TILES) {
        const int mt = t / NKT, kt = t - mt * NKT;
        src = A + (size_t)mt * 128 * K_TOT + kt * BK;
        dst = A_pk + (size_t)t * TILE_ELEMS;
    } else {
        const int t2 = t - A_TILES;
        const int nt = t2 / NKT, kt = t2 - nt * NKT;
        const int which = nt / 6;
        const int row0  = (nt - which * 6) * 128;
        const float* w = (which == 0) ? wq : (which == 1) ? wk : wv;
        src = w + (size_t)row0 * K_TOT + kt * BK;
        dst = W_pk + (size_t)t2 * TILE_ELEMS;
    }

    #pragma unroll
    for (int j = 0; j < 8; ++j) {
        int f = j * 256 + tid;
        int row = f >> 4, c4 = f & 15;
        float4 v = *reinterpret_cast<const float4*>(src + (size_t)row * K_TOT + c4 * 4);
        *reinterpret_cast<float4*>(&lds_f[row * LDSW + c4 * 4]) = v;
    }
    __syncthreads();

    #pragma unroll
    for (int j = 0; j < 4; ++j) {
        int c = j * 256 + tid;
        int kb = c >> 7, row = c & 127;
        const float* p = &lds_f[row * LDSW + kb * 8];
        u16x8 o;
        #pragma unroll
        for (int e = 0; e < 8; ++e) o[e] = f2bf_rne(p[e]);
        *reinterpret_cast<u16x8*>(dst + (size_t)c * 8) = o;
    }
}

// ---------------------------------------------------------------------------
// Pass 2: 128x256 bf16 MFMA GEMM with 3-slot LDS ring + counted vmcnt:
//   512 thr = 8 waves (2M x 4N), wave tile 64x64 (acc[4][4] f32x4).
//   Ring slots hold tiles t, t+1, t+2 -> before consuming tile t, exactly
//   tile t+1's 6 loads are newest outstanding -> s_waitcnt vmcnt(6), never 0.
//   4 phases/K-tile: {ds_read frags | 2 gld_lds stage | setprio(1) 8 MFMA},
//   per-phase s_barrier (scheduling only; correctness from tile-start sync).
//   Packed LDS [kb][row][8]: ds_read_b128 conflict-free by construction.
// ---------------------------------------------------------------------------
__global__ __launch_bounds__(512, 1) void qkv_gemm(
        const unsigned short* __restrict__ A_pk,
        const unsigned short* __restrict__ W_pk,
        const float* __restrict__ bias,
        float* __restrict__ out) {

    __shared__ __align__(16) unsigned short sA[3][TILE_ELEMS];      //  48 KiB
    __shared__ __align__(16) unsigned short sB[3][2 * TILE_ELEMS];  //  96 KiB

    const int tid  = threadIdx.x;
    const int lane = tid & 63;
    const int wid  = tid >> 6;     // 0..7
    const int wm   = wid >> 2;     // 0..1 : rows wm*64..+63
    const int wn   = wid & 3;      // 0..3 : cols wn*64..+63

    int bid = (int)blockIdx.x;
    bid = (bid & 7) * (NBLK / 8) + (bid >> 3);   // XCD-aware (bijective)
    const int bm = bid / NBN;
    const int bn = bid - bm * NBN;
    const int m0 = bm * BM;
    const int n0 = bn * BN;

    const unsigned short* aT  = A_pk + (size_t)bm * NKT * TILE_ELEMS;
    const unsigned short* bT0 = W_pk + (size_t)(2 * bn)     * NKT * TILE_ELEMS;
    const unsigned short* bT1 = W_pk + (size_t)(2 * bn + 1) * NKT * TILE_ELEMS;

    f32x4 acc[4][4];
    #pragma unroll
    for (int i = 0; i < 4; i++)
        #pragma unroll
        for (int j = 0; j < 4; j++)
            acc[i][j] = (f32x4){0.f, 0.f, 0.f, 0.f};

    // fragment read byte-offsets in packed slot [kb][row][8]:
    //   af[mi][kk] at aB + kk*8192 + mi*256 ; bf[nj][kk] at bB + kk*8192 + nj*256
    const int akb = lane >> 4;                       // 0..3
    const int aB  = akb * 2048 + (wm * 64 + (lane & 15)) * 16;
    const int bB  = (wn >> 1) * 16384 + akb * 2048 + ((wn & 1) * 64 + (lane & 15)) * 16;

    // prologue: stage tiles 0 and 1 into slots 0 and 1 (6 loads each)
    #pragma unroll
    for (int kt = 0; kt < 2; ++kt) {
        #pragma unroll
        for (int i = 0; i < 2; ++i) {
            int c = i * 512 + tid;
            gld_lds16(aT  + (size_t)kt * TILE_ELEMS + c * 8, &sA[kt][c * 8]);
        }
        #pragma unroll
        for (int i = 0; i < 2; ++i) {
            int c = i * 512 + tid;
            gld_lds16(bT0 + (size_t)kt * TILE_ELEMS + c * 8, &sB[kt][c * 8]);
        }
        #pragma unroll
        for (int i = 0; i < 2; ++i) {
            int c = i * 512 + tid;
            gld_lds16(bT1 + (size_t)kt * TILE_ELEMS + c * 8, &sB[kt][TILE_ELEMS + c * 8]);
        }
    }

    for (int t = 0; t < NKT; ++t) {
        const int s  = t % 3;
        const int s2 = (t + 2) % 3;         // stage target (holds tile t-1, retired)
        const bool st = (t + 2 < NKT);

        // ---- tile-start sync: own reads retired, tile t landed (counted vmcnt)
        asm volatile("s_waitcnt lgkmcnt(0)" ::: "memory");
        if (t < NKT - 1) { asm volatile("s_waitcnt vmcnt(6)" ::: "memory"); }
        else             { asm volatile("s_waitcnt vmcnt(0)" ::: "memory"); }
        __builtin_amdgcn_s_barrier();
        __builtin_amdgcn_sched_barrier(0);

        const char* pA = (const char*)&sA[s][0];
        const char* pB = (const char*)&sB[s][0];

        bf16x8 a0, a1, a2, a3, bfr[4];

        // ---- phase 0: kk=0, mi 0,1 ; stage A of tile t+2
        a0 = *(const bf16x8*)(pA + aB);
        a1 = *(const bf16x8*)(pA + aB + 256);
        #pragma unroll
        for (int j = 0; j < 4; ++j) bfr[j] = *(const bf16x8*)(pB + bB + j * 256);
        if (st) {
            #pragma unroll
            for (int i = 0; i < 2; ++i) {
                int c = i * 512 + tid;
                gld_lds16(aT + (size_t)(t + 2) * TILE_ELEMS + c * 8, &sA[s2][c * 8]);
            }
        }
        __builtin_amdgcn_s_setprio(1);
        #pragma unroll
        for (int j = 0; j < 4; ++j) {
            acc[0][j] = __builtin_amdgcn_mfma_f32_16x16x32_bf16(bfr[j], a0, acc[0][j], 0, 0, 0);
            acc[1][j] = __builtin_amdgcn_mfma_f32_16x16x32_bf16(bfr[j], a1, acc[1][j], 0, 0, 0);
        }
        __builtin_amdgcn_s_setprio(0);
        __builtin_amdgcn_s_barrier();

        // ---- phase 1: kk=0, mi 2,3 ; stage B-sub0 of tile t+2
        a2 = *(const bf16x8*)(pA + aB + 512);
        a3 = *(const bf16x8*)(pA + aB + 768);
        if (st) {
            #pragma unroll
            for (int i = 0; i < 2; ++i) {
                int c = i * 512 + tid;
                gld_lds16(bT0 + (size_t)(t + 2) * TILE_ELEMS + c * 8, &sB[s2][c * 8]);
            }
        }
        __builtin_amdgcn_s_setprio(1);
        #pragma unroll
        for (int j = 0; j < 4; ++j) {
            acc[2][j] = __builtin_amdgcn_mfma_f32_16x16x32_bf16(bfr[j], a2, acc[2][j], 0, 0, 0);
            acc[3][j] = __builtin_amdgcn_mfma_f32_16x16x32_bf16(bfr[j], a3, acc[3][j], 0, 0, 0);
        }
        __builtin_amdgcn_s_setprio(0);
        __builtin_amdgcn_s_barrier();

        // ---- phase 2: kk=1, mi 0,1 ; stage B-sub1 of tile t+2
        a0 = *(const bf16x8*)(pA + aB + 8192);
        a1 = *(const bf16x8*)(pA + aB + 8192 + 256);
        #pragma unroll
        for (int j = 0; j < 4; ++j) bfr[j] = *(const bf16x8*)(pB + bB + 8192 + j * 256);
        if (st) {
            #pragma unroll
            for (int i = 0; i < 2; ++i) {
                int c = i * 512 + tid;
                gld_lds16(bT1 + (size_t)(t + 2) * TILE_ELEMS + c * 8, &sB[s2][TILE_ELEMS + c * 8]);
            }
        }
        __builtin_amdgcn_s_setprio(1);
        #pragma unroll
        for (int j = 0; j < 4; ++j) {
            acc[0][j] = __builtin_amdgcn_mfma_f32_16x16x32_bf16(bfr[j], a0, acc[0][j], 0, 0, 0);
            acc[1][j] = __builtin_amdgcn_mfma_f32_16x16x32_bf16(bfr[j], a1, acc[1][j], 0, 0, 0);
        }
        __builtin_amdgcn_s_setprio(0);
        __builtin_amdgcn_s_barrier();

        // ---- phase 3: kk=1, mi 2,3 (no stage; next tile-start barrier follows)
        a2 = *(const bf16x8*)(pA + aB + 8192 + 512);
        a3 = *(const bf16x8*)(pA + aB + 8192 + 768);
        __builtin_amdgcn_s_setprio(1);
        #pragma unroll
        for (int j = 0; j < 4; ++j) {
            acc[2][j] = __builtin_amdgcn_mfma_f32_16x16x32_bf16(bfr[j], a2, acc[2][j], 0, 0, 0);
            acc[3][j] = __builtin_amdgcn_mfma_f32_16x16x32_bf16(bfr[j], a3, acc[3][j], 0, 0, 0);
        }
        __builtin_amdgcn_s_setprio(0);
    }

    // ---- epilogue: operand-swapped layout -> lane holds 4 consecutive n
    const int which = n0 / H;
    const int c0    = n0 - which * H;
    float* outB = out + (size_t)which * OUT_PER;

    #pragma unroll
    for (int j = 0; j < 4; ++j) {
        const int ncol = wn * 64 + j * 16 + ((lane >> 4) << 2);
        const float4 bv4 = *reinterpret_cast<const float4*>(&bias[n0 + ncol]);
        #pragma unroll
        for (int i = 0; i < 4; ++i) {
            const int mrow = m0 + wm * 64 + i * 16 + (lane & 15);
            float4 o;
            o.x = acc[i][j][0] + bv4.x;
            o.y = acc[i][j][1] + bv4.y;
            o.z = acc[i][j][2] + bv4.z;
            o.w = acc[i][j][3] + bv4.w;
            *reinterpret_cast<float4*>(&outB[(size_t)mrow * H + c0 + ncol]) = o;
        }
    }
}

extern "C" void kernel_launch(void* const* d_in, const int* in_sizes, int n_in,
                              void* d_out, int out_size, void* d_ws, size_t ws_size,
                              hipStream_t stream) {
    const float* hs = (const float*)d_in[0];
    const float* wq = (const float*)d_in[1];
    const float* bq = (const float*)d_in[2];
    const float* wk = (const float*)d_in[3];
    const float* bk = (const float*)d_in[4];
    const float* wv = (const float*)d_in[5];
    const float* bv = (const float*)d_in[6];

    unsigned short* A_pk = (unsigned short*)d_ws;
    unsigned short* W_pk = A_pk + (size_t)A_TILES * TILE_ELEMS;
    float* biasb         = (float*)(W_pk + (size_t)W_TILES * TILE_ELEMS);

    hipLaunchKernelGGL(convert_pack, dim3(A_TILES + W_TILES), dim3(256), 0, stream,
                       hs, wq, wk, wv, bq, bk, bv, A_pk, W_pk, biasb);

    hipLaunchKernelGGL(qkv_gemm, dim3(NBLK), dim3(512), 0, stream,
                       A_pk, W_pk, biasb, (float*)d_out);
}